// Round 5
// baseline (822.349 us; speedup 1.0000x reference)
//
#include <hip/hip_runtime.h>
#include <hip/hip_bf16.h>

#define IN_C   128
#define HC     128   // HEADS * OUT_C
#define OUT_C  64

// ---------------------------------------------------------------------------
// flags[0]=1 if float inputs are f32 (else bf16); flags[1]/[2]=1 if edge
// index buffers are int64 (else int32). Decided from raw bits on device.
// ---------------------------------------------------------------------------
__global__ void k_detect(const void* __restrict__ h,
                         const void* __restrict__ e1,
                         const void* __restrict__ e2,
                         int* __restrict__ flags)
{
    if (blockIdx.x == 0 && threadIdx.x == 0) {
        const unsigned short* u = (const unsigned short*)h;
        int f32 = 0;
        for (int k = 0; k < 512; ++k) {
            int ex = (u[k] >> 7) & 0xFF;
            if (ex >= 0xE0) { f32 = 1; break; }   // impossible for bf16 N(0,1)
        }
        flags[0] = f32;
        const int* a = (const int*)e1;
        const int* b = (const int*)e2;
        int any1 = 0, any2 = 0;
        for (int k = 0; k < 64; ++k) { any1 |= a[2*k+1]; any2 |= b[2*k+1]; }
        flags[1] = (any1 == 0);
        flags[2] = (any2 == 0);
    }
}

__device__ __forceinline__ float ldf(const void* p, int i, int f32) {
    if (f32) return ((const float*)p)[i];
    return __bfloat162float(((const __hip_bfloat16*)p)[i]);
}

__device__ __forceinline__ void load_edge(const void* ei, int e, int E, int i64,
                                          int& s, int& d)
{
    if (i64) {
        s = (int)((const long long*)ei)[e];
        d = (int)((const long long*)ei)[E + e];
    } else {
        s = ((const int*)ei)[e];
        d = ((const int*)ei)[E + e];
    }
}

// ---------------------------------------------------------------------------
// sentinel fill (diagnostic channel) — f32 now
// ---------------------------------------------------------------------------
__global__ void k_fill_sentinel(float* out, int total, float v)
{
    int i = blockIdx.x * blockDim.x + threadIdx.x;
    if (i < total) out[i] = v;
}

// ---------------------------------------------------------------------------
// K1: pure GEMM  xw = h @ W  (f32 out). block=128 (one column each), grid=N
// ---------------------------------------------------------------------------
__global__ __launch_bounds__(128)
void k_gemm(const void* __restrict__ h, const void* __restrict__ W,
            const int* __restrict__ flags, float* __restrict__ xw, int n)
{
    int node = blockIdx.x;
    if (node >= n) return;
    int j = threadIdx.x;
    int f32 = flags[0];

    __shared__ float hs[IN_C];
    hs[j] = ldf(h, node * IN_C + j, f32);
    __syncthreads();

    float acc = 0.f;
    if (f32) {
        const float* w = (const float*)W;
        #pragma unroll 8
        for (int k = 0; k < IN_C; ++k) acc += hs[k] * w[k * HC + j];
    } else {
        const __hip_bfloat16* w = (const __hip_bfloat16*)W;
        #pragma unroll 8
        for (int k = 0; k < IN_C; ++k) acc += hs[k] * __bfloat162float(w[k * HC + j]);
    }
    xw[(size_t)node * HC + j] = acc;
}

// ---------------------------------------------------------------------------
// K2: attention coefficients, scalar per (node, head).
// ---------------------------------------------------------------------------
__global__ __launch_bounds__(256)
void k_att(const float* __restrict__ xw,
           const void* __restrict__ att_s, const void* __restrict__ att_d,
           const int* __restrict__ flags,
           float* __restrict__ a_src, float* __restrict__ a_dst, int n)
{
    int i = blockIdx.x * blockDim.x + threadIdx.x;   // over n*2
    if (i >= n * 2) return;
    int node = i >> 1, hh = i & 1;
    int f32 = flags[0];
    const float* x = xw + (size_t)node * HC + hh * OUT_C;
    float vs = 0.f, vd = 0.f;
    #pragma unroll 8
    for (int c = 0; c < OUT_C; ++c) {
        float xv = x[c];
        vs += xv * ldf(att_s, hh * OUT_C + c, f32);
        vd += xv * ldf(att_d, hh * OUT_C + c, f32);
    }
    a_src[i] = vs;
    a_dst[i] = vd;
}

// ---------------------------------------------------------------------------
// K3: in-degree histogram
// ---------------------------------------------------------------------------
__global__ __launch_bounds__(256)
void k_deg(const void* __restrict__ ei, int E, int i64flag_idx,
           const int* __restrict__ flags, int* __restrict__ deg)
{
    int e = blockIdx.x * blockDim.x + threadIdx.x;
    if (e >= E) return;
    int s, d;
    load_edge(ei, e, E, flags[i64flag_idx], s, d);
    atomicAdd(&deg[d], 1);
}

// ---------------------------------------------------------------------------
// K4: exclusive scan over deg -> row_start[0..n], single block of 1024
// ---------------------------------------------------------------------------
__global__ __launch_bounds__(1024)
void k_scan(const int* __restrict__ deg, int* __restrict__ row_start, int n)
{
    __shared__ int buf[1024];
    __shared__ int base;
    if (threadIdx.x == 0) base = 0;
    __syncthreads();
    for (int start = 0; start < n; start += 1024) {
        int i = start + threadIdx.x;
        int v = (i < n) ? deg[i] : 0;
        buf[threadIdx.x] = v;
        __syncthreads();
        for (int off = 1; off < 1024; off <<= 1) {
            int t = (threadIdx.x >= off) ? buf[threadIdx.x - off] : 0;
            __syncthreads();
            buf[threadIdx.x] += t;
            __syncthreads();
        }
        if (i < n) row_start[i] = base + buf[threadIdx.x] - v;  // exclusive
        int chunk_total = buf[1023];
        __syncthreads();
        if (threadIdx.x == 0) base += chunk_total;
        __syncthreads();
    }
    if (threadIdx.x == 0) row_start[n] = base;
}

// ---------------------------------------------------------------------------
// K5: CSR fill — csr_src[slot] = src node of each incoming edge
// ---------------------------------------------------------------------------
__global__ __launch_bounds__(256)
void k_fill(const void* __restrict__ ei, int E, int i64flag_idx,
            const int* __restrict__ flags,
            const int* __restrict__ row_start, int* __restrict__ cursor,
            int* __restrict__ csr_src)
{
    int e = blockIdx.x * blockDim.x + threadIdx.x;
    if (e >= E) return;
    int s, d;
    load_edge(ei, e, E, flags[i64flag_idx], s, d);
    int pos = atomicAdd(&cursor[d], 1);
    csr_src[row_start[d] + pos] = s;
}

// ---------------------------------------------------------------------------
// K6: per-destination softmax + gather-aggregate + bias + ELU (+ combine).
// One wave per node; lane = channel within head. Exact max-subtraction.
// FIRST=1: out = elu(acc+bias)                       (stage conv-pc, f32)
// FIRST=0: out = 0.5*(staged + elu(acc+bias))        (final, f32)
// ---------------------------------------------------------------------------
template <int FIRST>
__global__ __launch_bounds__(256)
void k_node(const int* __restrict__ row_start, const int* __restrict__ csr_src,
            const float* __restrict__ a_src, const float* __restrict__ a_dst,
            const float* __restrict__ xw, const void* __restrict__ bias,
            const int* __restrict__ flags,
            float* __restrict__ out, int n)
{
    int node = blockIdx.x * 4 + (threadIdx.x >> 6);
    int lane = threadIdx.x & 63;
    if (node >= n) return;
    int beg = row_start[node], end = row_start[node + 1];
    float ad0 = a_dst[node * 2 + 0], ad1 = a_dst[node * 2 + 1];

    // pass 1: per-head max over incident edges
    float m0 = -1e30f, m1 = -1e30f;
    for (int t = beg + lane; t < end; t += 64) {
        int s = csr_src[t];
        float e0 = a_src[s * 2 + 0] + ad0; e0 = e0 > 0.f ? e0 : 0.2f * e0;
        float e1 = a_src[s * 2 + 1] + ad1; e1 = e1 > 0.f ? e1 : 0.2f * e1;
        m0 = fmaxf(m0, e0); m1 = fmaxf(m1, e1);
    }
    #pragma unroll
    for (int off = 32; off > 0; off >>= 1) {
        m0 = fmaxf(m0, __shfl_xor(m0, off));
        m1 = fmaxf(m1, __shfl_xor(m1, off));
    }
    if (end == beg) { m0 = 0.f; m1 = 0.f; }   // ref's isfinite guard

    // pass 2: denominators
    float s0 = 0.f, s1 = 0.f;
    for (int t = beg + lane; t < end; t += 64) {
        int s = csr_src[t];
        float e0 = a_src[s * 2 + 0] + ad0; e0 = e0 > 0.f ? e0 : 0.2f * e0;
        float e1 = a_src[s * 2 + 1] + ad1; e1 = e1 > 0.f ? e1 : 0.2f * e1;
        s0 += expf(e0 - m0);
        s1 += expf(e1 - m1);
    }
    #pragma unroll
    for (int off = 32; off > 0; off >>= 1) {
        s0 += __shfl_xor(s0, off);
        s1 += __shfl_xor(s1, off);
    }
    float inv0 = 1.f / (s0 + 1e-16f), inv1 = 1.f / (s1 + 1e-16f);

    // pass 3: weighted gather; lane = channel
    float acc0 = 0.f, acc1 = 0.f;
    for (int t = beg; t < end; ++t) {
        int s = csr_src[t];                       // uniform across wave
        float e0 = a_src[s * 2 + 0] + ad0; e0 = e0 > 0.f ? e0 : 0.2f * e0;
        float e1 = a_src[s * 2 + 1] + ad1; e1 = e1 > 0.f ? e1 : 0.2f * e1;
        float al0 = expf(e0 - m0) * inv0;
        float al1 = expf(e1 - m1) * inv1;
        const float* xr = xw + (size_t)s * HC;
        acc0 += al0 * xr[lane];
        acc1 += al1 * xr[OUT_C + lane];
    }

    int f32 = flags[0];
    float v0 = acc0 + ldf(bias, lane, f32);
    float v1 = acc1 + ldf(bias, OUT_C + lane, f32);
    v0 = v0 > 0.f ? v0 : expf(v0) - 1.f;
    v1 = v1 > 0.f ? v1 : expf(v1) - 1.f;

    size_t o = (size_t)node * HC + lane;
    if (FIRST) {
        out[o]         = v0;
        out[o + OUT_C] = v1;
    } else {
        out[o]         = 0.5f * (out[o] + v0);
        out[o + OUT_C] = 0.5f * (out[o + OUT_C] + v1);
    }
}

extern "C" void kernel_launch(void* const* d_in, const int* in_sizes, int n_in,
                              void* d_out, int out_size, void* d_ws, size_t ws_size,
                              hipStream_t stream)
{
    const void* node_h = d_in[0];
    const void* ei_pc  = d_in[1];
    const void* ei_mc  = d_in[2];
    const void* W_pc   = d_in[3];
    const void* as_pc  = d_in[4];
    const void* ad_pc  = d_in[5];
    const void* b_pc   = d_in[6];
    const void* W_mc   = d_in[7];
    const void* as_mc  = d_in[8];
    const void* ad_mc  = d_in[9];
    const void* b_mc   = d_in[10];

    const int N = in_sizes[0] / IN_C;
    const int E = in_sizes[1] / 2;
    const int total = N * HC;
    float* out = (float*)d_out;
    const int fillBlocks = (out_size + 255) / 256;

    // ---- host-side interface guards (diagnostic sentinel channel) ----
    {
        float sentinel = 0.f;
        if (n_in < 11) sentinel = 690.f;
        else if (in_sizes[1] != in_sizes[2]) sentinel = 702.f;
        else if (in_sizes[3] != IN_C * HC)   sentinel = 703.f;
        else if (in_sizes[4] != HC)          sentinel = 704.f;
        else if (in_sizes[5] != HC)          sentinel = 705.f;
        else if (in_sizes[6] != HC)          sentinel = 706.f;
        else if (in_sizes[7] != IN_C * HC)   sentinel = 707.f;
        else if (in_sizes[10] != HC)         sentinel = 710.f;
        else if (out_size != total)          sentinel = 720.f;
        size_t need = 256 + (size_t)total * 4 + 4 * (size_t)N * 2 * 4
                    + 2 * (size_t)N * 4 + ((size_t)N + 1) * 4 + (size_t)E * 4;
        if (sentinel == 0.f && ws_size < need) sentinel = 555.f;
        if (sentinel != 0.f) {
            k_fill_sentinel<<<fillBlocks, 256, 0, stream>>>(out, out_size, sentinel);
            return;
        }
    }

    // ---- workspace layout (~30.3 MB) ----
    char* p = (char*)d_ws;
    int* flags = (int*)p;              p += 256;
    float* xw = (float*)p;             p += (size_t)total * 4;      // 25.6 MB
    float* a_src = (float*)p;          p += (size_t)N * 2 * 4;
    float* a_dst = (float*)p;          p += (size_t)N * 2 * 4;
    char* zbase = p;
    int* deg = (int*)p;                p += (size_t)N * 4;
    int* cursor = (int*)p;             p += (size_t)N * 4;
    size_t zbytes = (size_t)(p - zbase);
    int* row_start = (int*)p;          p += ((size_t)N + 1) * 4;
    int* csr_src = (int*)p;            p += (size_t)E * 4;

    k_detect<<<1, 64, 0, stream>>>(node_h, ei_pc, ei_mc, flags);

    const int blocksE = (E + 255) / 256;
    const int blocksA = (2 * N + 255) / 256;
    const int blocksN = (N + 3) / 4;

    // ---- conv PC ----
    hipMemsetAsync(zbase, 0, zbytes, stream);
    k_gemm<<<N, 128, 0, stream>>>(node_h, W_pc, flags, xw, N);
    k_att<<<blocksA, 256, 0, stream>>>(xw, as_pc, ad_pc, flags, a_src, a_dst, N);
    k_deg<<<blocksE, 256, 0, stream>>>(ei_pc, E, 1, flags, deg);
    k_scan<<<1, 1024, 0, stream>>>(deg, row_start, N);
    k_fill<<<blocksE, 256, 0, stream>>>(ei_pc, E, 1, flags, row_start, cursor, csr_src);
    k_node<1><<<blocksN, 256, 0, stream>>>(row_start, csr_src, a_src, a_dst, xw, b_pc, flags, out, N);

    // ---- conv MC ----
    hipMemsetAsync(zbase, 0, zbytes, stream);
    k_gemm<<<N, 128, 0, stream>>>(node_h, W_mc, flags, xw, N);
    k_att<<<blocksA, 256, 0, stream>>>(xw, as_mc, ad_mc, flags, a_src, a_dst, N);
    k_deg<<<blocksE, 256, 0, stream>>>(ei_mc, E, 2, flags, deg);
    k_scan<<<1, 1024, 0, stream>>>(deg, row_start, N);
    k_fill<<<blocksE, 256, 0, stream>>>(ei_mc, E, 2, flags, row_start, cursor, csr_src);
    k_node<0><<<blocksN, 256, 0, stream>>>(row_start, csr_src, a_src, a_dst, xw, b_mc, flags, out, N);
}

// Round 6
// 637.195 us; speedup vs baseline: 1.2906x; 1.2906x over previous
//
#include <hip/hip_runtime.h>
#include <hip/hip_bf16.h>

#define IN_C   128
#define HC     128   // HEADS * OUT_C
#define OUT_C  64
#define NPB    64    // nodes per block in k_gemm2
#define NCH    8     // nodes per LDS chunk in k_gemm2

// ---------------------------------------------------------------------------
// flags[0]=1 if float inputs are f32 (else bf16); flags[1]/[2]=1 if edge
// index buffers are int64 (else int32).
// ---------------------------------------------------------------------------
__global__ void k_detect(const void* __restrict__ h,
                         const void* __restrict__ e1,
                         const void* __restrict__ e2,
                         int* __restrict__ flags)
{
    if (blockIdx.x == 0 && threadIdx.x == 0) {
        const unsigned short* u = (const unsigned short*)h;
        int f32 = 0;
        for (int k = 0; k < 512; ++k) {
            int ex = (u[k] >> 7) & 0xFF;
            if (ex >= 0xE0) { f32 = 1; break; }
        }
        flags[0] = f32;
        const int* a = (const int*)e1;
        const int* b = (const int*)e2;
        int any1 = 0, any2 = 0;
        for (int k = 0; k < 64; ++k) { any1 |= a[2*k+1]; any2 |= b[2*k+1]; }
        flags[1] = (any1 == 0);
        flags[2] = (any2 == 0);
    }
}

__device__ __forceinline__ float ldf(const void* p, int i, int f32) {
    if (f32) return ((const float*)p)[i];
    return __bfloat162float(((const __hip_bfloat16*)p)[i]);
}

__device__ __forceinline__ void load_edge(const void* ei, int e, int E, int i64,
                                          int& s, int& d)
{
    if (i64) {
        s = (int)((const long long*)ei)[e];
        d = (int)((const long long*)ei)[E + e];
    } else {
        s = ((const int*)ei)[e];
        d = ((const int*)ei)[E + e];
    }
}

__global__ void k_fill_sentinel(float* out, int total, float v)
{
    int i = blockIdx.x * blockDim.x + threadIdx.x;
    if (i < total) out[i] = v;
}

// ---------------------------------------------------------------------------
// K1: fused GEMM + attention coefficients.
// W staged once per block in LDS (bf16). 64 nodes/block, 8-node chunks,
// 4 accumulators/thread. Per-wave shuffle reduce for a_src/a_dst.
// xw written bf16 (feeds the k_node gather).
// ---------------------------------------------------------------------------
__global__ __launch_bounds__(256)
void k_gemm2(const void* __restrict__ h, const void* __restrict__ W,
             const void* __restrict__ att_s, const void* __restrict__ att_d,
             const int* __restrict__ flags,
             __hip_bfloat16* __restrict__ xw,
             float* __restrict__ a_src, float* __restrict__ a_dst, int n)
{
    __shared__ __hip_bfloat16 Wl[IN_C][HC];   // 32 KB
    __shared__ float hsl[NCH][IN_C];          // 4 KB
    int tid = threadIdx.x;
    int f32 = flags[0];

    for (int idx = tid; idx < IN_C * HC; idx += 256)
        Wl[idx >> 7][idx & 127] = __float2bfloat16(ldf(W, idx, f32));

    int base = blockIdx.x * NPB;
    int j = tid & 127, half = tid >> 7;
    float att_sj = ldf(att_s, j, f32);
    float att_dj = ldf(att_d, j, f32);
    int head = j >> 6;

    for (int c0 = 0; c0 < NPB; c0 += NCH) {
        __syncthreads();                       // protect hsl (and 1st-iter W)
        for (int idx = tid; idx < NCH * IN_C; idx += 256) {
            int r = idx >> 7, c = idx & 127;
            int nd = base + c0 + r;
            hsl[r][c] = (nd < n) ? ldf(h, nd * IN_C + c, f32) : 0.f;
        }
        __syncthreads();

        float acc[4] = {0.f, 0.f, 0.f, 0.f};
        #pragma unroll 4
        for (int k = 0; k < IN_C; ++k) {
            float w = __bfloat162float(Wl[k][j]);
            #pragma unroll
            for (int nn = 0; nn < 4; ++nn)
                acc[nn] += hsl[half * 4 + nn][k] * w;
        }

        #pragma unroll
        for (int nn = 0; nn < 4; ++nn) {
            int nd = base + c0 + half * 4 + nn;
            float vs = acc[nn] * att_sj;
            float vd = acc[nn] * att_dj;
            #pragma unroll
            for (int off = 32; off; off >>= 1) {
                vs += __shfl_xor(vs, off);
                vd += __shfl_xor(vd, off);
            }
            if (nd < n) {
                xw[(size_t)nd * HC + j] = __float2bfloat16(acc[nn]);
                if ((tid & 63) == 0) {
                    a_src[nd * 2 + head] = vs;
                    a_dst[nd * 2 + head] = vd;
                }
            }
        }
    }
}

// ---------------------------------------------------------------------------
// K2: in-degree histogram
// ---------------------------------------------------------------------------
__global__ __launch_bounds__(256)
void k_deg(const void* __restrict__ ei, int E, int i64flag_idx,
           const int* __restrict__ flags, int* __restrict__ deg)
{
    int e = blockIdx.x * blockDim.x + threadIdx.x;
    if (e >= E) return;
    int s, d;
    load_edge(ei, e, E, flags[i64flag_idx], s, d);
    atomicAdd(&deg[d], 1);
}

// ---------------------------------------------------------------------------
// K3: exclusive scan, two-phase (serial per-thread + one 1024-wide scan)
// ---------------------------------------------------------------------------
__global__ __launch_bounds__(1024)
void k_scan(const int* __restrict__ deg, int* __restrict__ row_start, int n)
{
    __shared__ int partial[1024];
    int t = threadIdx.x;
    int C = (n + 1023) >> 10;
    int lo = t * C, hi = lo + C;
    if (lo > n) lo = n;
    if (hi > n) hi = n;
    int s = 0;
    for (int i = lo; i < hi; ++i) s += deg[i];
    partial[t] = s;
    __syncthreads();
    for (int off = 1; off < 1024; off <<= 1) {
        int v = (t >= off) ? partial[t - off] : 0;
        __syncthreads();
        partial[t] += v;
        __syncthreads();
    }
    int run = t ? partial[t - 1] : 0;
    for (int i = lo; i < hi; ++i) { row_start[i] = run; run += deg[i]; }
    if (t == 0) row_start[n] = partial[1023];
}

// ---------------------------------------------------------------------------
// K4: CSR fill
// ---------------------------------------------------------------------------
__global__ __launch_bounds__(256)
void k_fill(const void* __restrict__ ei, int E, int i64flag_idx,
            const int* __restrict__ flags,
            const int* __restrict__ row_start, int* __restrict__ cursor,
            int* __restrict__ csr_src)
{
    int e = blockIdx.x * blockDim.x + threadIdx.x;
    if (e >= E) return;
    int s, d;
    load_edge(ei, e, E, flags[i64flag_idx], s, d);
    int pos = atomicAdd(&cursor[d], 1);
    csr_src[row_start[d] + pos] = s;
}

// ---------------------------------------------------------------------------
// K5: per-destination softmax + gather-aggregate + bias + ELU (+ combine).
// One wave per node. Lane l owns channels {2l, 2l+1} (head = l>=32).
// Alphas computed once per edge by one lane, shuffle-broadcast to the wave.
// xw gathered as packed bf16 pairs (one dword/lane -> 256B/edge).
// ---------------------------------------------------------------------------
template <int FIRST>
__global__ __launch_bounds__(256)
void k_node(const int* __restrict__ row_start, const int* __restrict__ csr_src,
            const float* __restrict__ a_src, const float* __restrict__ a_dst,
            const __hip_bfloat16* __restrict__ xw, const void* __restrict__ bias,
            const int* __restrict__ flags,
            float* __restrict__ out, int n)
{
    int node = blockIdx.x * 4 + (threadIdx.x >> 6);
    int lane = threadIdx.x & 63;
    if (node >= n) return;
    int beg = row_start[node], end = row_start[node + 1];
    int deg = end - beg;
    const float2* as2 = (const float2*)a_src;
    float2 ad = ((const float2*)a_dst)[node];

    // cached first edge for this lane
    int   s_c = 0;
    float e0_c = -1e30f, e1_c = -1e30f;
    bool have = (lane < deg);
    if (have) {
        s_c = csr_src[beg + lane];
        float2 as = as2[s_c];
        e0_c = as.x + ad.x; e0_c = e0_c > 0.f ? e0_c : 0.2f * e0_c;
        e1_c = as.y + ad.y; e1_c = e1_c > 0.f ? e1_c : 0.2f * e1_c;
    }

    // pass 1: max
    float m0 = e0_c, m1 = e1_c;
    for (int t = beg + lane + 64; t < end; t += 64) {
        int s = csr_src[t];
        float2 as = as2[s];
        float e0 = as.x + ad.x; e0 = e0 > 0.f ? e0 : 0.2f * e0;
        float e1 = as.y + ad.y; e1 = e1 > 0.f ? e1 : 0.2f * e1;
        m0 = fmaxf(m0, e0); m1 = fmaxf(m1, e1);
    }
    #pragma unroll
    for (int off = 32; off; off >>= 1) {
        m0 = fmaxf(m0, __shfl_xor(m0, off));
        m1 = fmaxf(m1, __shfl_xor(m1, off));
    }
    if (deg == 0) { m0 = 0.f; m1 = 0.f; }

    // pass 2: denominators
    float s0 = have ? expf(e0_c - m0) : 0.f;
    float s1 = have ? expf(e1_c - m1) : 0.f;
    for (int t = beg + lane + 64; t < end; t += 64) {
        int s = csr_src[t];
        float2 as = as2[s];
        float e0 = as.x + ad.x; e0 = e0 > 0.f ? e0 : 0.2f * e0;
        float e1 = as.y + ad.y; e1 = e1 > 0.f ? e1 : 0.2f * e1;
        s0 += expf(e0 - m0);
        s1 += expf(e1 - m1);
    }
    #pragma unroll
    for (int off = 32; off; off >>= 1) {
        s0 += __shfl_xor(s0, off);
        s1 += __shfl_xor(s1, off);
    }
    float inv0 = 1.f / (s0 + 1e-16f), inv1 = 1.f / (s1 + 1e-16f);

    // pass 3: alpha broadcast + packed gather
    float accA = 0.f, accB = 0.f;     // channels 2*lane, 2*lane+1
    for (int chunk = beg; chunk < end; chunk += 64) {
        int cnt = end - chunk; if (cnt > 64) cnt = 64;
        float my0 = 0.f, my1 = 0.f; int mys = 0;
        if (chunk == beg) {
            if (have) {
                mys = s_c;
                my0 = expf(e0_c - m0) * inv0;
                my1 = expf(e1_c - m1) * inv1;
            }
        } else if (lane < cnt) {
            mys = csr_src[chunk + lane];
            float2 as = as2[mys];
            float e0 = as.x + ad.x; e0 = e0 > 0.f ? e0 : 0.2f * e0;
            float e1 = as.y + ad.y; e1 = e1 > 0.f ? e1 : 0.2f * e1;
            my0 = expf(e0 - m0) * inv0;
            my1 = expf(e1 - m1) * inv1;
        }
        for (int i = 0; i < cnt; ++i) {
            int s    = __shfl(mys, i);
            float a0 = __shfl(my0, i);
            float a1 = __shfl(my1, i);
            float al = (lane < 32) ? a0 : a1;
            unsigned v = ((const unsigned*)(xw + (size_t)s * HC))[lane];
            float xa = __uint_as_float(v << 16);
            float xb = __uint_as_float(v & 0xFFFF0000u);
            accA += al * xa;
            accB += al * xb;
        }
    }

    int f32 = flags[0];
    int c0 = lane * 2;
    float v0 = accA + ldf(bias, c0, f32);
    float v1 = accB + ldf(bias, c0 + 1, f32);
    v0 = v0 > 0.f ? v0 : expf(v0) - 1.f;
    v1 = v1 > 0.f ? v1 : expf(v1) - 1.f;

    float2* o2 = (float2*)(out + (size_t)node * HC + c0);
    if (FIRST) {
        *o2 = make_float2(v0, v1);
    } else {
        float2 pr = *o2;
        *o2 = make_float2(0.5f * (pr.x + v0), 0.5f * (pr.y + v1));
    }
}

extern "C" void kernel_launch(void* const* d_in, const int* in_sizes, int n_in,
                              void* d_out, int out_size, void* d_ws, size_t ws_size,
                              hipStream_t stream)
{
    const void* node_h = d_in[0];
    const void* ei_pc  = d_in[1];
    const void* ei_mc  = d_in[2];
    const void* W_pc   = d_in[3];
    const void* as_pc  = d_in[4];
    const void* ad_pc  = d_in[5];
    const void* b_pc   = d_in[6];
    const void* W_mc   = d_in[7];
    const void* as_mc  = d_in[8];
    const void* ad_mc  = d_in[9];
    const void* b_mc   = d_in[10];

    const int N = in_sizes[0] / IN_C;
    const int E = in_sizes[1] / 2;
    const int total = N * HC;
    float* out = (float*)d_out;
    const int fillBlocks = (out_size + 255) / 256;

    // ---- host-side interface guards ----
    {
        float sentinel = 0.f;
        if (n_in < 11) sentinel = 690.f;
        else if (in_sizes[1] != in_sizes[2]) sentinel = 702.f;
        else if (in_sizes[3] != IN_C * HC)   sentinel = 703.f;
        else if (in_sizes[7] != IN_C * HC)   sentinel = 707.f;
        else if (out_size != total)          sentinel = 720.f;
        size_t need = 256 + (size_t)total * 2 + 2 * (size_t)N * 2 * 4
                    + 3 * (size_t)N * 4 + 64 + (size_t)E * 4;
        if (sentinel == 0.f && ws_size < need) sentinel = 555.f;
        if (sentinel != 0.f) {
            k_fill_sentinel<<<fillBlocks, 256, 0, stream>>>(out, out_size, sentinel);
            return;
        }
    }

    // ---- workspace layout (~17.4 MB) ----
    char* p = (char*)d_ws;
    int* flags = (int*)p;                    p += 256;
    __hip_bfloat16* xw = (__hip_bfloat16*)p; p += (size_t)total * 2;   // 12.8 MB
    float* a_src = (float*)p;                p += (size_t)N * 2 * 4;
    float* a_dst = (float*)p;                p += (size_t)N * 2 * 4;
    char* zbase = p;
    int* deg = (int*)p;                      p += (size_t)N * 4;
    int* cursor = (int*)p;                   p += (size_t)N * 4;
    size_t zbytes = (size_t)(p - zbase);
    int* row_start = (int*)p;                p += ((size_t)N + 1) * 4;
    int* csr_src = (int*)p;                  p += (size_t)E * 4;

    k_detect<<<1, 64, 0, stream>>>(node_h, ei_pc, ei_mc, flags);

    const int blocksE = (E + 255) / 256;
    const int blocksN = (N + 3) / 4;
    const int blocksG = (N + NPB - 1) / NPB;

    // ---- conv PC ----
    hipMemsetAsync(zbase, 0, zbytes, stream);
    k_gemm2<<<blocksG, 256, 0, stream>>>(node_h, W_pc, as_pc, ad_pc, flags, xw, a_src, a_dst, N);
    k_deg<<<blocksE, 256, 0, stream>>>(ei_pc, E, 1, flags, deg);
    k_scan<<<1, 1024, 0, stream>>>(deg, row_start, N);
    k_fill<<<blocksE, 256, 0, stream>>>(ei_pc, E, 1, flags, row_start, cursor, csr_src);
    k_node<1><<<blocksN, 256, 0, stream>>>(row_start, csr_src, a_src, a_dst, xw, b_pc, flags, out, N);

    // ---- conv MC ----
    hipMemsetAsync(zbase, 0, zbytes, stream);
    k_gemm2<<<blocksG, 256, 0, stream>>>(node_h, W_mc, as_mc, ad_mc, flags, xw, a_src, a_dst, N);
    k_deg<<<blocksE, 256, 0, stream>>>(ei_mc, E, 2, flags, deg);
    k_scan<<<1, 1024, 0, stream>>>(deg, row_start, N);
    k_fill<<<blocksE, 256, 0, stream>>>(ei_mc, E, 2, flags, row_start, cursor, csr_src);
    k_node<0><<<blocksN, 256, 0, stream>>>(row_start, csr_src, a_src, a_dst, xw, b_mc, flags, out, N);
}

// Round 7
// 442.520 us; speedup vs baseline: 1.8583x; 1.4399x over previous
//
#include <hip/hip_runtime.h>
#include <hip/hip_bf16.h>

#define IN_C   128
#define HC     128   // HEADS * OUT_C
#define OUT_C  64

typedef short bf16x8 __attribute__((ext_vector_type(8)));
typedef float f32x4  __attribute__((ext_vector_type(4)));

__device__ __forceinline__ unsigned short f2bf(float f) {
    unsigned u = __float_as_uint(f);
    return (unsigned short)((u + 0x7FFF + ((u >> 16) & 1)) >> 16);   // RNE
}

// ---------------------------------------------------------------------------
// flags[0]=1 if float inputs f32; flags[1]/[2]=1 if edges int64; flags[3]=mfma-bad
// ---------------------------------------------------------------------------
__global__ void k_detect(const void* __restrict__ h,
                         const void* __restrict__ e1,
                         const void* __restrict__ e2,
                         int* __restrict__ flags)
{
    if (blockIdx.x == 0 && threadIdx.x == 0) {
        const unsigned short* u = (const unsigned short*)h;
        int f32 = 0;
        for (int k = 0; k < 512; ++k) {
            int ex = (u[k] >> 7) & 0xFF;
            if (ex >= 0xE0) { f32 = 1; break; }
        }
        flags[0] = f32;
        const int* a = (const int*)e1;
        const int* b = (const int*)e2;
        int any1 = 0, any2 = 0;
        for (int k = 0; k < 64; ++k) { any1 |= a[2*k+1]; any2 |= b[2*k+1]; }
        flags[1] = (any1 == 0);
        flags[2] = (any2 == 0);
        flags[3] = 0;
    }
}

__device__ __forceinline__ float ldf(const void* p, int i, int f32) {
    if (f32) return ((const float*)p)[i];
    return __bfloat162float(((const __hip_bfloat16*)p)[i]);
}

__device__ __forceinline__ void load_edge(const void* ei, int e, int E, int i64,
                                          int& s, int& d)
{
    if (i64) {
        s = (int)((const long long*)ei)[e];
        d = (int)((const long long*)ei)[E + e];
    } else {
        s = ((const int*)ei)[e];
        d = ((const int*)ei)[E + e];
    }
}

__global__ void k_fill_sentinel(float* out, int total, float v)
{
    int i = blockIdx.x * blockDim.x + threadIdx.x;
    if (i < total) out[i] = v;
}

// ---------------------------------------------------------------------------
// K0: transpose both W -> bf16 W^T[col][k]
// ---------------------------------------------------------------------------
__global__ __launch_bounds__(256)
void k_prep(const void* __restrict__ Wpc, const void* __restrict__ Wmc,
            const int* __restrict__ flags,
            unsigned short* __restrict__ WTpc, unsigned short* __restrict__ WTmc)
{
    int idx = blockIdx.x * 256 + threadIdx.x;
    if (idx >= 2 * IN_C * HC) return;
    int conv = idx >= IN_C * HC;
    int r = idx - conv * IN_C * HC;
    int k = r >> 7, j = r & 127;
    float v = ldf(conv ? Wmc : Wpc, r, flags[0]);
    (conv ? WTmc : WTpc)[(size_t)j * IN_C + k] = f2bf(v);
}

// ---------------------------------------------------------------------------
// K1: MFMA GEMM, both convs, + fused attention coefficients.
// wave = 16-row strip; 8 col-tiles x 4 K-steps of 16x16x32 bf16 MFMA.
// A from global h (cvt to bf16), B from global W^T (L2-resident). No LDS.
// ---------------------------------------------------------------------------
__global__ __launch_bounds__(256)
void k_gemm_mfma(const void* __restrict__ h,
                 const unsigned short* __restrict__ WT_pc,
                 const unsigned short* __restrict__ WT_mc,
                 const void* __restrict__ as_pc, const void* __restrict__ ad_pc,
                 const void* __restrict__ as_mc, const void* __restrict__ ad_mc,
                 const int* __restrict__ flags,
                 unsigned short* __restrict__ xw_pc, unsigned short* __restrict__ xw_mc,
                 float* __restrict__ oas_pc, float* __restrict__ oad_pc,
                 float* __restrict__ oas_mc, float* __restrict__ oad_mc,
                 int n)
{
    int tid = threadIdx.x;
    int wave = tid >> 6, lane = tid & 63;
    int cl = lane & 15, grp = lane >> 4;
    int base = blockIdx.x * 64 + wave * 16;
    int f32 = flags[0];

    // A fragments: row = base+cl, k = 32*s + 8*grp + [0..8)
    int nodeLoad = base + cl;
    int nl = nodeLoad < n ? nodeLoad : (n - 1);   // clamp; garbage rows never stored
    bf16x8 afr[4];
    #pragma unroll
    for (int s = 0; s < 4; ++s) {
        int k0 = 32 * s + 8 * grp;
        if (f32) {
            const float* hr = (const float*)h + (size_t)nl * IN_C + k0;
            #pragma unroll
            for (int j = 0; j < 8; ++j) afr[s][j] = (short)f2bf(hr[j]);
        } else {
            const unsigned short* hr = (const unsigned short*)h + (size_t)nl * IN_C + k0;
            #pragma unroll
            for (int j = 0; j < 8; ++j) afr[s][j] = (short)hr[j];
        }
    }

    #pragma unroll
    for (int conv = 0; conv < 2; ++conv) {
        const unsigned short* WT = conv ? WT_mc : WT_pc;
        const void* atS = conv ? as_mc : as_pc;
        const void* atD = conv ? ad_mc : ad_pc;
        unsigned short* xw = conv ? xw_mc : xw_pc;
        float* oaS = conv ? oas_mc : oas_pc;
        float* oaD = conv ? oad_mc : oad_pc;

        float vs_[4][2] = {{0.f,0.f},{0.f,0.f},{0.f,0.f},{0.f,0.f}};
        float vd_[4][2] = {{0.f,0.f},{0.f,0.f},{0.f,0.f},{0.f,0.f}};

        #pragma unroll
        for (int t = 0; t < 8; ++t) {
            int col = t * 16 + cl;
            f32x4 acc = {0.f, 0.f, 0.f, 0.f};
            #pragma unroll
            for (int s = 0; s < 4; ++s) {
                int k0 = 32 * s + 8 * grp;
                bf16x8 b = *(const bf16x8*)(WT + (size_t)col * IN_C + k0);
                acc = __builtin_amdgcn_mfma_f32_16x16x32_bf16(afr[s], b, acc, 0, 0, 0);
            }
            float aS = ldf(atS, col, f32);
            float aD = ldf(atD, col, f32);
            int hd = t >> 2;
            #pragma unroll
            for (int r = 0; r < 4; ++r) {
                int nodeOut = base + 4 * grp + r;    // D: row=(lane>>4)*4+r, col=lane&15
                float v = acc[r];
                if (nodeOut < n) xw[(size_t)nodeOut * HC + col] = f2bf(v);
                vs_[r][hd] += v * aS;
                vd_[r][hd] += v * aD;
            }
        }
        #pragma unroll
        for (int r = 0; r < 4; ++r) {
            #pragma unroll
            for (int hd = 0; hd < 2; ++hd) {
                float vs = vs_[r][hd], vd = vd_[r][hd];
                #pragma unroll
                for (int off = 1; off < 16; off <<= 1) {
                    vs += __shfl_xor(vs, off);
                    vd += __shfl_xor(vd, off);
                }
                int nodeOut = base + 4 * grp + r;
                if (cl == 0 && nodeOut < n) {
                    oaS[nodeOut * 2 + hd] = vs;
                    oaD[nodeOut * 2 + hd] = vd;
                }
            }
        }
    }
}

// ---------------------------------------------------------------------------
// K1b: verify MFMA row 0 vs scalar f32 dot; set flags[3] on mismatch
// ---------------------------------------------------------------------------
__global__ __launch_bounds__(256)
void k_verify(const void* __restrict__ h,
              const void* __restrict__ Wpc, const void* __restrict__ Wmc,
              const unsigned short* __restrict__ xw_pc,
              const unsigned short* __restrict__ xw_mc,
              int* __restrict__ flags)
{
    int tid = threadIdx.x;
    int j = tid & 127, conv = tid >> 7;
    int f32 = flags[0];
    const void* W = conv ? Wmc : Wpc;
    const unsigned short* xw = conv ? xw_mc : xw_pc;
    float dot = 0.f;
    for (int k = 0; k < IN_C; ++k)
        dot += ldf(h, k, f32) * ldf(W, k * HC + j, f32);
    float got = __uint_as_float(((unsigned)xw[j]) << 16);
    if (fabsf(dot - got) > 0.25f) atomicOr(&flags[3], 1);
}

// ---------------------------------------------------------------------------
// K1c: gated VALU fallback GEMM (runs only if flags[3] != 0)
// ---------------------------------------------------------------------------
#define NPB 64
#define NCH 8
__global__ __launch_bounds__(256)
void k_fb(const void* __restrict__ h, const void* __restrict__ W,
          const void* __restrict__ att_s, const void* __restrict__ att_d,
          const int* __restrict__ flags,
          unsigned short* __restrict__ xw,
          float* __restrict__ a_src, float* __restrict__ a_dst, int n)
{
    if (flags[3] == 0) return;      // uniform early-exit
    __shared__ __hip_bfloat16 Wl[IN_C][HC];
    __shared__ float hsl[NCH][IN_C];
    int tid = threadIdx.x;
    int f32 = flags[0];

    for (int idx = tid; idx < IN_C * HC; idx += 256)
        Wl[idx >> 7][idx & 127] = __float2bfloat16(ldf(W, idx, f32));

    int base = blockIdx.x * NPB;
    int j = tid & 127, half = tid >> 7;
    float att_sj = ldf(att_s, j, f32);
    float att_dj = ldf(att_d, j, f32);
    int head = j >> 6;

    for (int c0 = 0; c0 < NPB; c0 += NCH) {
        __syncthreads();
        for (int idx = tid; idx < NCH * IN_C; idx += 256) {
            int r = idx >> 7, c = idx & 127;
            int nd = base + c0 + r;
            hsl[r][c] = (nd < n) ? ldf(h, nd * IN_C + c, f32) : 0.f;
        }
        __syncthreads();

        float acc[4] = {0.f, 0.f, 0.f, 0.f};
        #pragma unroll 4
        for (int k = 0; k < IN_C; ++k) {
            float w = __bfloat162float(Wl[k][j]);
            #pragma unroll
            for (int nn = 0; nn < 4; ++nn)
                acc[nn] += hsl[half * 4 + nn][k] * w;
        }
        #pragma unroll
        for (int nn = 0; nn < 4; ++nn) {
            int nd = base + c0 + half * 4 + nn;
            float vs = acc[nn] * att_sj;
            float vd = acc[nn] * att_dj;
            #pragma unroll
            for (int off = 32; off; off >>= 1) {
                vs += __shfl_xor(vs, off);
                vd += __shfl_xor(vd, off);
            }
            if (nd < n) {
                xw[(size_t)nd * HC + j] = f2bf(acc[nn]);
                if ((tid & 63) == 0) {
                    a_src[nd * 2 + head] = vs;
                    a_dst[nd * 2 + head] = vd;
                }
            }
        }
    }
}

// ---------------------------------------------------------------------------
// K2: in-degree histogram, both convs in one launch
// ---------------------------------------------------------------------------
__global__ __launch_bounds__(256)
void k_deg2(const void* __restrict__ e1, const void* __restrict__ e2, int E,
            const int* __restrict__ flags,
            int* __restrict__ deg1, int* __restrict__ deg2)
{
    int i = blockIdx.x * blockDim.x + threadIdx.x;
    if (i >= 2 * E) return;
    int conv = i >= E;
    int e = i - conv * E;
    int s, d;
    load_edge(conv ? e2 : e1, e, E, flags[1 + conv], s, d);
    atomicAdd(&(conv ? deg2 : deg1)[d], 1);
}

// ---------------------------------------------------------------------------
// K3: exclusive scan (two-phase), one block per conv
// ---------------------------------------------------------------------------
__global__ __launch_bounds__(1024)
void k_scan2(const int* __restrict__ deg1, const int* __restrict__ deg2,
             int* __restrict__ row1, int* __restrict__ row2, int n)
{
    const int* deg = blockIdx.x ? deg2 : deg1;
    int* row_start  = blockIdx.x ? row2 : row1;
    __shared__ int partial[1024];
    int t = threadIdx.x;
    int C = (n + 1023) >> 10;
    int lo = t * C, hi = lo + C;
    if (lo > n) lo = n;
    if (hi > n) hi = n;
    int s = 0;
    for (int i = lo; i < hi; ++i) s += deg[i];
    partial[t] = s;
    __syncthreads();
    for (int off = 1; off < 1024; off <<= 1) {
        int v = (t >= off) ? partial[t - off] : 0;
        __syncthreads();
        partial[t] += v;
        __syncthreads();
    }
    int run = t ? partial[t - 1] : 0;
    for (int i = lo; i < hi; ++i) { row_start[i] = run; run += deg[i]; }
    if (t == 0) row_start[n] = partial[1023];
}

// ---------------------------------------------------------------------------
// K4: CSR fill, both convs
// ---------------------------------------------------------------------------
__global__ __launch_bounds__(256)
void k_fill2(const void* __restrict__ e1, const void* __restrict__ e2, int E,
             const int* __restrict__ flags,
             const int* __restrict__ row1, const int* __restrict__ row2,
             int* __restrict__ cur1, int* __restrict__ cur2,
             int* __restrict__ csr1, int* __restrict__ csr2)
{
    int i = blockIdx.x * blockDim.x + threadIdx.x;
    if (i >= 2 * E) return;
    int conv = i >= E;
    int e = i - conv * E;
    int s, d;
    load_edge(conv ? e2 : e1, e, E, flags[1 + conv], s, d);
    int pos = atomicAdd(&(conv ? cur2 : cur1)[d], 1);
    (conv ? csr2 : csr1)[(conv ? row2 : row1)[d] + pos] = s;
}

// ---------------------------------------------------------------------------
// K5: per-destination softmax + gather-aggregate + bias + ELU (+ combine)
// ---------------------------------------------------------------------------
template <int FIRST>
__global__ __launch_bounds__(256)
void k_node(const int* __restrict__ row_start, const int* __restrict__ csr_src,
            const float* __restrict__ a_src, const float* __restrict__ a_dst,
            const unsigned short* __restrict__ xw, const void* __restrict__ bias,
            const int* __restrict__ flags,
            float* __restrict__ out, int n)
{
    int node = blockIdx.x * 4 + (threadIdx.x >> 6);
    int lane = threadIdx.x & 63;
    if (node >= n) return;
    int beg = row_start[node], end = row_start[node + 1];
    int deg = end - beg;
    const float2* as2 = (const float2*)a_src;
    float2 ad = ((const float2*)a_dst)[node];

    int   s_c = 0;
    float e0_c = -1e30f, e1_c = -1e30f;
    bool have = (lane < deg);
    if (have) {
        s_c = csr_src[beg + lane];
        float2 as = as2[s_c];
        e0_c = as.x + ad.x; e0_c = e0_c > 0.f ? e0_c : 0.2f * e0_c;
        e1_c = as.y + ad.y; e1_c = e1_c > 0.f ? e1_c : 0.2f * e1_c;
    }

    float m0 = e0_c, m1 = e1_c;
    for (int t = beg + lane + 64; t < end; t += 64) {
        int s = csr_src[t];
        float2 as = as2[s];
        float e0 = as.x + ad.x; e0 = e0 > 0.f ? e0 : 0.2f * e0;
        float e1 = as.y + ad.y; e1 = e1 > 0.f ? e1 : 0.2f * e1;
        m0 = fmaxf(m0, e0); m1 = fmaxf(m1, e1);
    }
    #pragma unroll
    for (int off = 32; off; off >>= 1) {
        m0 = fmaxf(m0, __shfl_xor(m0, off));
        m1 = fmaxf(m1, __shfl_xor(m1, off));
    }
    if (deg == 0) { m0 = 0.f; m1 = 0.f; }

    float s0 = have ? expf(e0_c - m0) : 0.f;
    float s1 = have ? expf(e1_c - m1) : 0.f;
    for (int t = beg + lane + 64; t < end; t += 64) {
        int s = csr_src[t];
        float2 as = as2[s];
        float e0 = as.x + ad.x; e0 = e0 > 0.f ? e0 : 0.2f * e0;
        float e1 = as.y + ad.y; e1 = e1 > 0.f ? e1 : 0.2f * e1;
        s0 += expf(e0 - m0);
        s1 += expf(e1 - m1);
    }
    #pragma unroll
    for (int off = 32; off; off >>= 1) {
        s0 += __shfl_xor(s0, off);
        s1 += __shfl_xor(s1, off);
    }
    float inv0 = 1.f / (s0 + 1e-16f), inv1 = 1.f / (s1 + 1e-16f);

    float accA = 0.f, accB = 0.f;
    for (int chunk = beg; chunk < end; chunk += 64) {
        int cnt = end - chunk; if (cnt > 64) cnt = 64;
        float my0 = 0.f, my1 = 0.f; int mys = 0;
        if (chunk == beg) {
            if (have) {
                mys = s_c;
                my0 = expf(e0_c - m0) * inv0;
                my1 = expf(e1_c - m1) * inv1;
            }
        } else if (lane < cnt) {
            mys = csr_src[chunk + lane];
            float2 as = as2[mys];
            float e0 = as.x + ad.x; e0 = e0 > 0.f ? e0 : 0.2f * e0;
            float e1 = as.y + ad.y; e1 = e1 > 0.f ? e1 : 0.2f * e1;
            my0 = expf(e0 - m0) * inv0;
            my1 = expf(e1 - m1) * inv1;
        }
        for (int i = 0; i < cnt; ++i) {
            int s    = __shfl(mys, i);
            float a0 = __shfl(my0, i);
            float a1 = __shfl(my1, i);
            float al = (lane < 32) ? a0 : a1;
            unsigned v = ((const unsigned*)(xw + (size_t)s * HC))[lane];
            float xa = __uint_as_float(v << 16);
            float xb = __uint_as_float(v & 0xFFFF0000u);
            accA += al * xa;
            accB += al * xb;
        }
    }

    int f32 = flags[0];
    int c0 = lane * 2;
    float v0 = accA + ldf(bias, c0, f32);
    float v1 = accB + ldf(bias, c0 + 1, f32);
    v0 = v0 > 0.f ? v0 : expf(v0) - 1.f;
    v1 = v1 > 0.f ? v1 : expf(v1) - 1.f;

    float2* o2 = (float2*)(out + (size_t)node * HC + c0);
    if (FIRST) {
        *o2 = make_float2(v0, v1);
    } else {
        float2 pr = *o2;
        *o2 = make_float2(0.5f * (pr.x + v0), 0.5f * (pr.y + v1));
    }
}

extern "C" void kernel_launch(void* const* d_in, const int* in_sizes, int n_in,
                              void* d_out, int out_size, void* d_ws, size_t ws_size,
                              hipStream_t stream)
{
    const void* node_h = d_in[0];
    const void* ei_pc  = d_in[1];
    const void* ei_mc  = d_in[2];
    const void* W_pc   = d_in[3];
    const void* as_pc  = d_in[4];
    const void* ad_pc  = d_in[5];
    const void* b_pc   = d_in[6];
    const void* W_mc   = d_in[7];
    const void* as_mc  = d_in[8];
    const void* ad_mc  = d_in[9];
    const void* b_mc   = d_in[10];

    const int N = in_sizes[0] / IN_C;
    const int E = in_sizes[1] / 2;
    const int total = N * HC;
    float* out = (float*)d_out;
    const int fillBlocks = (out_size + 255) / 256;

    // ---- workspace layout (~35 MB) ----
    char* p = (char*)d_ws;
    int* flags = (int*)p;                     p += 256;
    unsigned short* WT_pc = (unsigned short*)p; p += (size_t)IN_C * HC * 2;
    unsigned short* WT_mc = (unsigned short*)p; p += (size_t)IN_C * HC * 2;
    unsigned short* xw_pc = (unsigned short*)p; p += (size_t)total * 2;
    unsigned short* xw_mc = (unsigned short*)p; p += (size_t)total * 2;
    float* aspc = (float*)p;                  p += (size_t)N * 2 * 4;
    float* adpc = (float*)p;                  p += (size_t)N * 2 * 4;
    float* asmc = (float*)p;                  p += (size_t)N * 2 * 4;
    float* admc = (float*)p;                  p += (size_t)N * 2 * 4;
    char* zbase = p;
    int* deg1 = (int*)p;                      p += (size_t)N * 4;
    int* cur1 = (int*)p;                      p += (size_t)N * 4;
    int* deg2 = (int*)p;                      p += (size_t)N * 4;
    int* cur2 = (int*)p;                      p += (size_t)N * 4;
    size_t zbytes = (size_t)(p - zbase);
    int* row1 = (int*)p;                      p += ((size_t)N + 1) * 4;
    int* row2 = (int*)p;                      p += ((size_t)N + 1) * 4;
    int* csr1 = (int*)p;                      p += (size_t)E * 4;
    int* csr2 = (int*)p;                      p += (size_t)E * 4;

    // ---- host-side interface guards ----
    {
        float sentinel = 0.f;
        if (n_in < 11) sentinel = 690.f;
        else if (in_sizes[1] != in_sizes[2]) sentinel = 702.f;
        else if (in_sizes[3] != IN_C * HC)   sentinel = 703.f;
        else if (in_sizes[7] != IN_C * HC)   sentinel = 707.f;
        else if (out_size != total)          sentinel = 720.f;
        size_t need = (size_t)(p - (char*)d_ws);
        if (sentinel == 0.f && ws_size < need) sentinel = 555.f;
        if (sentinel != 0.f) {
            k_fill_sentinel<<<fillBlocks, 256, 0, stream>>>(out, out_size, sentinel);
            return;
        }
    }

    k_detect<<<1, 64, 0, stream>>>(node_h, ei_pc, ei_mc, flags);
    hipMemsetAsync(zbase, 0, zbytes, stream);

    k_prep<<<(2 * IN_C * HC + 255) / 256, 256, 0, stream>>>(W_pc, W_mc, flags, WT_pc, WT_mc);

    const int blocks2E = (2 * E + 255) / 256;
    k_deg2<<<blocks2E, 256, 0, stream>>>(ei_pc, ei_mc, E, flags, deg1, deg2);
    k_scan2<<<2, 1024, 0, stream>>>(deg1, deg2, row1, row2, N);
    k_fill2<<<blocks2E, 256, 0, stream>>>(ei_pc, ei_mc, E, flags, row1, row2, cur1, cur2, csr1, csr2);

    const int blocksG = (N + 63) / 64;
    k_gemm_mfma<<<blocksG, 256, 0, stream>>>(node_h, WT_pc, WT_mc,
                                             as_pc, ad_pc, as_mc, ad_mc, flags,
                                             xw_pc, xw_mc, aspc, adpc, asmc, admc, N);
    k_verify<<<1, 256, 0, stream>>>(node_h, W_pc, W_mc, xw_pc, xw_mc, flags);
    k_fb<<<(N + NPB - 1) / NPB, 256, 0, stream>>>(node_h, W_pc, as_pc, ad_pc, flags, xw_pc, aspc, adpc, N);
    k_fb<<<(N + NPB - 1) / NPB, 256, 0, stream>>>(node_h, W_mc, as_mc, ad_mc, flags, xw_mc, asmc, admc, N);

    const int blocksN = (N + 3) / 4;
    k_node<1><<<blocksN, 256, 0, stream>>>(row1, csr1, aspc, adpc, xw_pc, b_pc, flags, out, N);
    k_node<0><<<blocksN, 256, 0, stream>>>(row2, csr2, asmc, admc, xw_mc, b_mc, flags, out, N);
}

// Round 8
// 216.638 us; speedup vs baseline: 3.7960x; 2.0427x over previous
//
#include <hip/hip_runtime.h>
#include <hip/hip_bf16.h>

#define IN_C   128
#define HC     128   // HEADS * OUT_C
#define OUT_C  64
#define EPB    4096  // edges per block in bucket kernels
#define NBMAX  1024

typedef short bf16x8 __attribute__((ext_vector_type(8)));
typedef float f32x4  __attribute__((ext_vector_type(4)));

__device__ __forceinline__ unsigned short f2bf(float f) {
    unsigned u = __float_as_uint(f);
    return (unsigned short)((u + 0x7FFF + ((u >> 16) & 1)) >> 16);   // RNE
}

// ---------------------------------------------------------------------------
// flags[0]=1 if float inputs f32; flags[1]/[2]=1 if edges int64
// ---------------------------------------------------------------------------
__global__ void k_detect(const void* __restrict__ h,
                         const void* __restrict__ e1,
                         const void* __restrict__ e2,
                         int* __restrict__ flags)
{
    if (blockIdx.x == 0 && threadIdx.x == 0) {
        const unsigned short* u = (const unsigned short*)h;
        int f32 = 0;
        for (int k = 0; k < 512; ++k) {
            int ex = (u[k] >> 7) & 0xFF;
            if (ex >= 0xE0) { f32 = 1; break; }
        }
        flags[0] = f32;
        const int* a = (const int*)e1;
        const int* b = (const int*)e2;
        int any1 = 0, any2 = 0;
        for (int k = 0; k < 64; ++k) { any1 |= a[2*k+1]; any2 |= b[2*k+1]; }
        flags[1] = (any1 == 0);
        flags[2] = (any2 == 0);
        flags[3] = 0;
    }
}

__device__ __forceinline__ float ldf(const void* p, int i, int f32) {
    if (f32) return ((const float*)p)[i];
    return __bfloat162float(((const __hip_bfloat16*)p)[i]);
}

__device__ __forceinline__ void load_edge(const void* ei, int e, int E, int i64,
                                          int& s, int& d)
{
    if (i64) {
        s = (int)((const long long*)ei)[e];
        d = (int)((const long long*)ei)[E + e];
    } else {
        s = ((const int*)ei)[e];
        d = ((const int*)ei)[E + e];
    }
}

__global__ void k_fill_sentinel(float* out, int total, float v)
{
    int i = blockIdx.x * blockDim.x + threadIdx.x;
    if (i < total) out[i] = v;
}

// ---------------------------------------------------------------------------
// K0: transpose both W -> bf16 W^T[col][k]
// ---------------------------------------------------------------------------
__global__ __launch_bounds__(256)
void k_prep(const void* __restrict__ Wpc, const void* __restrict__ Wmc,
            const int* __restrict__ flags,
            unsigned short* __restrict__ WTpc, unsigned short* __restrict__ WTmc)
{
    int idx = blockIdx.x * 256 + threadIdx.x;
    if (idx >= 2 * IN_C * HC) return;
    int conv = idx >= IN_C * HC;
    int r = idx - conv * IN_C * HC;
    int k = r >> 7, j = r & 127;
    float v = ldf(conv ? Wmc : Wpc, r, flags[0]);
    (conv ? WTmc : WTpc)[(size_t)j * IN_C + k] = f2bf(v);
}

// ---------------------------------------------------------------------------
// K1: MFMA GEMM, both convs, + fused attention coefficients (validated r6/r7)
// ---------------------------------------------------------------------------
__global__ __launch_bounds__(256)
void k_gemm_mfma(const void* __restrict__ h,
                 const unsigned short* __restrict__ WT_pc,
                 const unsigned short* __restrict__ WT_mc,
                 const void* __restrict__ as_pc, const void* __restrict__ ad_pc,
                 const void* __restrict__ as_mc, const void* __restrict__ ad_mc,
                 const int* __restrict__ flags,
                 unsigned short* __restrict__ xw_pc, unsigned short* __restrict__ xw_mc,
                 float* __restrict__ oas_pc, float* __restrict__ oad_pc,
                 float* __restrict__ oas_mc, float* __restrict__ oad_mc,
                 int n)
{
    int tid = threadIdx.x;
    int wave = tid >> 6, lane = tid & 63;
    int cl = lane & 15, grp = lane >> 4;
    int base = blockIdx.x * 64 + wave * 16;
    int f32 = flags[0];

    int nodeLoad = base + cl;
    int nl = nodeLoad < n ? nodeLoad : (n - 1);
    bf16x8 afr[4];
    #pragma unroll
    for (int s = 0; s < 4; ++s) {
        int k0 = 32 * s + 8 * grp;
        if (f32) {
            const float* hr = (const float*)h + (size_t)nl * IN_C + k0;
            #pragma unroll
            for (int j = 0; j < 8; ++j) afr[s][j] = (short)f2bf(hr[j]);
        } else {
            const unsigned short* hr = (const unsigned short*)h + (size_t)nl * IN_C + k0;
            #pragma unroll
            for (int j = 0; j < 8; ++j) afr[s][j] = (short)hr[j];
        }
    }

    #pragma unroll
    for (int conv = 0; conv < 2; ++conv) {
        const unsigned short* WT = conv ? WT_mc : WT_pc;
        const void* atS = conv ? as_mc : as_pc;
        const void* atD = conv ? ad_mc : ad_pc;
        unsigned short* xw = conv ? xw_mc : xw_pc;
        float* oaS = conv ? oas_mc : oas_pc;
        float* oaD = conv ? oad_mc : oad_pc;

        float vs_[4][2] = {{0.f,0.f},{0.f,0.f},{0.f,0.f},{0.f,0.f}};
        float vd_[4][2] = {{0.f,0.f},{0.f,0.f},{0.f,0.f},{0.f,0.f}};

        #pragma unroll
        for (int t = 0; t < 8; ++t) {
            int col = t * 16 + cl;
            f32x4 acc = {0.f, 0.f, 0.f, 0.f};
            #pragma unroll
            for (int s = 0; s < 4; ++s) {
                int k0 = 32 * s + 8 * grp;
                bf16x8 b = *(const bf16x8*)(WT + (size_t)col * IN_C + k0);
                acc = __builtin_amdgcn_mfma_f32_16x16x32_bf16(afr[s], b, acc, 0, 0, 0);
            }
            float aS = ldf(atS, col, f32);
            float aD = ldf(atD, col, f32);
            int hd = t >> 2;
            #pragma unroll
            for (int r = 0; r < 4; ++r) {
                int nodeOut = base + 4 * grp + r;
                float v = acc[r];
                if (nodeOut < n) xw[(size_t)nodeOut * HC + col] = f2bf(v);
                vs_[r][hd] += v * aS;
                vd_[r][hd] += v * aD;
            }
        }
        #pragma unroll
        for (int r = 0; r < 4; ++r) {
            #pragma unroll
            for (int hd = 0; hd < 2; ++hd) {
                float vs = vs_[r][hd], vd = vd_[r][hd];
                #pragma unroll
                for (int off = 1; off < 16; off <<= 1) {
                    vs += __shfl_xor(vs, off);
                    vd += __shfl_xor(vd, off);
                }
                int nodeOut = base + 4 * grp + r;
                if (cl == 0 && nodeOut < n) {
                    oaS[nodeOut * 2 + hd] = vs;
                    oaD[nodeOut * 2 + hd] = vd;
                }
            }
        }
    }
}

// ---------------------------------------------------------------------------
// CSR build, two-level bucket sort. bucket = dst >> 7 (128 nodes/bucket).
// ---------------------------------------------------------------------------
// A: bucket histogram (LDS-reduced)
__global__ __launch_bounds__(256)
void k_bhist(const void* __restrict__ ei, int E, int i64flag_idx,
             const int* __restrict__ flags, int NB, int* __restrict__ gbh)
{
    __shared__ int cnt[NBMAX];
    int tid = threadIdx.x;
    for (int i = tid; i < NB; i += 256) cnt[i] = 0;
    __syncthreads();
    int base = blockIdx.x * EPB;
    int i64 = flags[i64flag_idx];
    for (int k = 0; k < EPB / 256; ++k) {
        int e = base + k * 256 + tid;
        if (e < E) {
            int s, d; load_edge(ei, e, E, i64, s, d);
            atomicAdd(&cnt[d >> 7], 1);
        }
    }
    __syncthreads();
    for (int i = tid; i < NB; i += 256)
        if (cnt[i]) atomicAdd(&gbh[i], cnt[i]);
}

// B: exclusive scan of bucket counts
__global__ __launch_bounds__(1024)
void k_bscan(const int* __restrict__ gbh, int* __restrict__ bbase, int NB, int E)
{
    __shared__ int buf[1024];
    int t = threadIdx.x;
    int v = (t < NB) ? gbh[t] : 0;
    buf[t] = v;
    __syncthreads();
    for (int o = 1; o < 1024; o <<= 1) {
        int x = (t >= o) ? buf[t - o] : 0;
        __syncthreads();
        buf[t] += x;
        __syncthreads();
    }
    if (t < NB) bbase[t] = buf[t] - v;
    if (t == 0) bbase[NB] = E;
}

// C: scatter packed (dst,src) into bucket regions; per-block contiguous runs
__global__ __launch_bounds__(256)
void k_bscatter(const void* __restrict__ ei, int E, int i64flag_idx,
                const int* __restrict__ flags, int NB,
                const int* __restrict__ bbase, int* __restrict__ gcur,
                unsigned long long* __restrict__ bkt)
{
    __shared__ int cnt[NBMAX];
    __shared__ int lbase[NBMAX];
    int tid = threadIdx.x;
    for (int i = tid; i < NB; i += 256) cnt[i] = 0;
    __syncthreads();
    int base = blockIdx.x * EPB;
    int i64 = flags[i64flag_idx];
    for (int k = 0; k < EPB / 256; ++k) {
        int e = base + k * 256 + tid;
        if (e < E) {
            int s, d; load_edge(ei, e, E, i64, s, d);
            atomicAdd(&cnt[d >> 7], 1);
        }
    }
    __syncthreads();
    for (int i = tid; i < NB; i += 256) {
        int c = cnt[i];
        lbase[i] = c ? atomicAdd(&gcur[i], c) : 0;
        cnt[i] = 0;
    }
    __syncthreads();
    for (int k = 0; k < EPB / 256; ++k) {
        int e = base + k * 256 + tid;
        if (e < E) {
            int s, d; load_edge(ei, e, E, i64, s, d);
            int b = d >> 7;
            int pos = atomicAdd(&cnt[b], 1);
            bkt[(size_t)bbase[b] + lbase[b] + pos] =
                ((unsigned long long)(unsigned)d << 32) | (unsigned)s;
        }
    }
}

// D: per-bucket local CSR; writes row_start + csr segment sequentially
__global__ __launch_bounds__(256)
void k_bcsr(const unsigned long long* __restrict__ bkt,
            const int* __restrict__ bbase,
            int* __restrict__ row_start, int* __restrict__ csr,
            int NB, int n, int E)
{
    __shared__ int cnt[128], off[128], exc[128];
    int b = blockIdx.x, tid = threadIdx.x;
    int nb0 = b << 7;
    int nd = n - nb0; if (nd > 128) nd = 128;
    int bb = bbase[b], be = bbase[b + 1];
    if (tid < 128) cnt[tid] = 0;
    __syncthreads();
    for (int i = bb + tid; i < be; i += 256)
        atomicAdd(&cnt[(int)(bkt[i] >> 32) - nb0], 1);
    __syncthreads();
    int v = (tid < 128) ? cnt[tid] : 0;
    if (tid < 128) off[tid] = v;
    __syncthreads();
    for (int o = 1; o < 128; o <<= 1) {
        int x = (tid < 128 && tid >= o) ? off[tid - o] : 0;
        __syncthreads();
        if (tid < 128) off[tid] += x;
        __syncthreads();
    }
    if (tid < 128) exc[tid] = off[tid] - v;
    if (tid < nd) row_start[nb0 + tid] = bb + exc[tid];
    if (b == NB - 1 && tid == 0) row_start[n] = E;
    if (tid < 128) cnt[tid] = 0;
    __syncthreads();
    for (int i = bb + tid; i < be; i += 256) {
        unsigned long long pd = bkt[i];
        int d = (int)(pd >> 32) - nb0;
        int pos = atomicAdd(&cnt[d], 1);
        csr[bb + exc[d] + pos] = (int)(unsigned)pd;
    }
}

// ---------------------------------------------------------------------------
// K5 v3: per-destination softmax + gather + bias + ELU (+ combine).
// One wave/node. Gather: 2 edges/iteration, half-wave each, dwordx2 loads.
// Alphas + srcs staged in per-wave LDS (broadcast ds_read, no shuffles).
// ---------------------------------------------------------------------------
template <int FIRST>
__global__ __launch_bounds__(256)
void k_node3(const int* __restrict__ row_start, const int* __restrict__ csr_src,
             const float* __restrict__ a_src, const float* __restrict__ a_dst,
             const unsigned short* __restrict__ xw, const void* __restrict__ bias,
             const int* __restrict__ flags,
             float* __restrict__ out, int n)
{
    __shared__ int   slds[4][64];
    __shared__ float alds[4][2][64];
    int wv = threadIdx.x >> 6, lane = threadIdx.x & 63;
    int node = blockIdx.x * 4 + wv;
    if (node >= n) return;
    int beg = row_start[node], end = row_start[node + 1];
    int deg = end - beg;
    const float2* as2 = (const float2*)a_src;
    float2 ad = ((const float2*)a_dst)[node];

    // first-chunk edges cached in registers
    int   s_c = 0;
    float e0_c = -1e30f, e1_c = -1e30f;
    bool have = (lane < deg);
    if (have) {
        s_c = csr_src[beg + lane];
        float2 as = as2[s_c];
        e0_c = as.x + ad.x; e0_c = e0_c > 0.f ? e0_c : 0.2f * e0_c;
        e1_c = as.y + ad.y; e1_c = e1_c > 0.f ? e1_c : 0.2f * e1_c;
    }

    // max
    float m0 = e0_c, m1 = e1_c;
    for (int t = beg + lane + 64; t < end; t += 64) {
        int s = csr_src[t];
        float2 as = as2[s];
        float e0 = as.x + ad.x; e0 = e0 > 0.f ? e0 : 0.2f * e0;
        float e1 = as.y + ad.y; e1 = e1 > 0.f ? e1 : 0.2f * e1;
        m0 = fmaxf(m0, e0); m1 = fmaxf(m1, e1);
    }
    #pragma unroll
    for (int off = 32; off; off >>= 1) {
        m0 = fmaxf(m0, __shfl_xor(m0, off));
        m1 = fmaxf(m1, __shfl_xor(m1, off));
    }
    if (deg == 0) { m0 = 0.f; m1 = 0.f; }

    // denom
    float s0 = have ? expf(e0_c - m0) : 0.f;
    float s1 = have ? expf(e1_c - m1) : 0.f;
    for (int t = beg + lane + 64; t < end; t += 64) {
        int s = csr_src[t];
        float2 as = as2[s];
        float e0 = as.x + ad.x; e0 = e0 > 0.f ? e0 : 0.2f * e0;
        float e1 = as.y + ad.y; e1 = e1 > 0.f ? e1 : 0.2f * e1;
        s0 += expf(e0 - m0);
        s1 += expf(e1 - m1);
    }
    #pragma unroll
    for (int off = 32; off; off >>= 1) {
        s0 += __shfl_xor(s0, off);
        s1 += __shfl_xor(s1, off);
    }
    float inv0 = 1.f / (s0 + 1e-16f), inv1 = 1.f / (s1 + 1e-16f);

    // gather: 2 edges per iteration
    int l5 = lane & 31, sub = lane >> 5, hbit = l5 >> 4;
    float acc0 = 0.f, acc1 = 0.f, acc2 = 0.f, acc3 = 0.f;
    for (int chunk = beg; chunk < end; chunk += 64) {
        int cnt = end - chunk; if (cnt > 64) cnt = 64;
        float a0 = 0.f, a1 = 0.f; int ss = 0;
        if (chunk == beg) {
            if (have) {
                ss = s_c;
                a0 = expf(e0_c - m0) * inv0;
                a1 = expf(e1_c - m1) * inv1;
            }
        } else if (lane < cnt) {
            ss = csr_src[chunk + lane];
            float2 as = as2[ss];
            float e0 = as.x + ad.x; e0 = e0 > 0.f ? e0 : 0.2f * e0;
            float e1 = as.y + ad.y; e1 = e1 > 0.f ? e1 : 0.2f * e1;
            a0 = expf(e0 - m0) * inv0;
            a1 = expf(e1 - m1) * inv1;
        }
        slds[wv][lane] = ss;            // wave-local LDS, wave-synchronous
        alds[wv][0][lane] = a0;
        alds[wv][1][lane] = a1;
        int pairs = (cnt + 1) >> 1;
        for (int i = 0; i < pairs; ++i) {
            int eidx = 2 * i + sub;     // padded slots have alpha=0, src=0
            int src = slds[wv][eidx];
            float al = alds[wv][hbit][eidx];
            const uint2* rp = (const uint2*)(xw + (size_t)src * HC) + l5;
            uint2 v = *rp;
            acc0 += al * __uint_as_float(v.x << 16);
            acc1 += al * __uint_as_float(v.x & 0xFFFF0000u);
            acc2 += al * __uint_as_float(v.y << 16);
            acc3 += al * __uint_as_float(v.y & 0xFFFF0000u);
        }
    }
    acc0 += __shfl_xor(acc0, 32);
    acc1 += __shfl_xor(acc1, 32);
    acc2 += __shfl_xor(acc2, 32);
    acc3 += __shfl_xor(acc3, 32);

    if (sub == 0) {
        int f32 = flags[0];
        int c0 = l5 * 4;
        float v0 = acc0 + ldf(bias, c0 + 0, f32);
        float v1 = acc1 + ldf(bias, c0 + 1, f32);
        float v2 = acc2 + ldf(bias, c0 + 2, f32);
        float v3 = acc3 + ldf(bias, c0 + 3, f32);
        v0 = v0 > 0.f ? v0 : expf(v0) - 1.f;
        v1 = v1 > 0.f ? v1 : expf(v1) - 1.f;
        v2 = v2 > 0.f ? v2 : expf(v2) - 1.f;
        v3 = v3 > 0.f ? v3 : expf(v3) - 1.f;
        float4* o4 = (float4*)(out + (size_t)node * HC + c0);
        if (FIRST) {
            *o4 = make_float4(v0, v1, v2, v3);
        } else {
            float4 pr = *o4;
            *o4 = make_float4(0.5f * (pr.x + v0), 0.5f * (pr.y + v1),
                              0.5f * (pr.z + v2), 0.5f * (pr.w + v3));
        }
    }
}

extern "C" void kernel_launch(void* const* d_in, const int* in_sizes, int n_in,
                              void* d_out, int out_size, void* d_ws, size_t ws_size,
                              hipStream_t stream)
{
    const void* node_h = d_in[0];
    const void* ei_pc  = d_in[1];
    const void* ei_mc  = d_in[2];
    const void* W_pc   = d_in[3];
    const void* as_pc  = d_in[4];
    const void* ad_pc  = d_in[5];
    const void* b_pc   = d_in[6];
    const void* W_mc   = d_in[7];
    const void* as_mc  = d_in[8];
    const void* ad_mc  = d_in[9];
    const void* b_mc   = d_in[10];

    const int N = in_sizes[0] / IN_C;
    const int E = in_sizes[1] / 2;
    const int total = N * HC;
    const int NB = (N + 127) >> 7;
    float* out = (float*)d_out;
    const int fillBlocks = (out_size + 255) / 256;

    // ---- workspace layout (~40.5 MB) ----
    char* p = (char*)d_ws;
    int* flags = (int*)p;                       p += 256;
    unsigned short* WT_pc = (unsigned short*)p; p += (size_t)IN_C * HC * 2;
    unsigned short* WT_mc = (unsigned short*)p; p += (size_t)IN_C * HC * 2;
    unsigned short* xw_pc = (unsigned short*)p; p += (size_t)total * 2;
    unsigned short* xw_mc = (unsigned short*)p; p += (size_t)total * 2;
    float* aspc = (float*)p;                    p += (size_t)N * 2 * 4;
    float* adpc = (float*)p;                    p += (size_t)N * 2 * 4;
    float* asmc = (float*)p;                    p += (size_t)N * 2 * 4;
    float* admc = (float*)p;                    p += (size_t)N * 2 * 4;
    char* zbase = p;                            // gbh + gcur zeroed per conv
    int* gbh  = (int*)p;                        p += (size_t)NBMAX * 4;
    int* gcur = (int*)p;                        p += (size_t)NBMAX * 4;
    size_t zbytes = (size_t)(p - zbase);
    int* bbase = (int*)p;                       p += (size_t)(NBMAX + 1) * 4;
    int* row1 = (int*)p;                        p += ((size_t)N + 1) * 4;
    int* row2 = (int*)p;                        p += ((size_t)N + 1) * 4;
    int* csr1 = (int*)p;                        p += (size_t)E * 4;
    int* csr2 = (int*)p;                        p += (size_t)E * 4;
    unsigned long long* bkt = (unsigned long long*)p; p += (size_t)E * 8;

    // ---- host-side interface guards ----
    {
        float sentinel = 0.f;
        if (n_in < 11) sentinel = 690.f;
        else if (in_sizes[1] != in_sizes[2]) sentinel = 702.f;
        else if (in_sizes[3] != IN_C * HC)   sentinel = 703.f;
        else if (in_sizes[7] != IN_C * HC)   sentinel = 707.f;
        else if (out_size != total)          sentinel = 720.f;
        else if (NB > NBMAX)                 sentinel = 730.f;
        size_t need = (size_t)(p - (char*)d_ws);
        if (sentinel == 0.f && ws_size < need) sentinel = 555.f;
        if (sentinel != 0.f) {
            k_fill_sentinel<<<fillBlocks, 256, 0, stream>>>(out, out_size, sentinel);
            return;
        }
    }

    k_detect<<<1, 64, 0, stream>>>(node_h, ei_pc, ei_mc, flags);
    k_prep<<<(2 * IN_C * HC + 255) / 256, 256, 0, stream>>>(W_pc, W_mc, flags, WT_pc, WT_mc);

    const int blocksG = (N + 63) / 64;
    k_gemm_mfma<<<blocksG, 256, 0, stream>>>(node_h, WT_pc, WT_mc,
                                             as_pc, ad_pc, as_mc, ad_mc, flags,
                                             xw_pc, xw_mc, aspc, adpc, asmc, admc, N);

    const int blocksB = (E + EPB - 1) / EPB;
    const int blocksN = (N + 3) / 4;

    // ---- conv PC: CSR build + node aggregate ----
    hipMemsetAsync(zbase, 0, zbytes, stream);
    k_bhist<<<blocksB, 256, 0, stream>>>(ei_pc, E, 1, flags, NB, gbh);
    k_bscan<<<1, 1024, 0, stream>>>(gbh, bbase, NB, E);
    k_bscatter<<<blocksB, 256, 0, stream>>>(ei_pc, E, 1, flags, NB, bbase, gcur, bkt);
    k_bcsr<<<NB, 256, 0, stream>>>(bkt, bbase, row1, csr1, NB, N, E);
    k_node3<1><<<blocksN, 256, 0, stream>>>(row1, csr1, aspc, adpc, xw_pc, b_pc, flags, out, N);

    // ---- conv MC ----
    hipMemsetAsync(zbase, 0, zbytes, stream);
    k_bhist<<<blocksB, 256, 0, stream>>>(ei_mc, E, 2, flags, NB, gbh);
    k_bscan<<<1, 1024, 0, stream>>>(gbh, bbase, NB, E);
    k_bscatter<<<blocksB, 256, 0, stream>>>(ei_mc, E, 2, flags, NB, bbase, gcur, bkt);
    k_bcsr<<<NB, 256, 0, stream>>>(bkt, bbase, row2, csr2, NB, N, E);
    k_node3<0><<<blocksN, 256, 0, stream>>>(row2, csr2, asmc, admc, xw_mc, b_mc, flags, out, N);
}